// Round 7
// baseline (3556.162 us; speedup 1.0000x reference)
//
#include <hip/hip_runtime.h>
#include <hip/hip_bf16.h>

// ESN scan: h_{t+1} = 0.1*h_t + 0.9*tanh(x_t @ Win^T + b + h_t @ W^T)
// B=32, T=1000, D=64, H=1024.
//
// R10: contention-cut XCD-local scan (R8 protocol, R9 lessons).
// R9 post-mortem: 1024-thr blocks @ 1 block/CU = 4 waves/SIMD = 128-VGPR
// cap; inner loop needs ~155 live VGPRs -> spill -> scratch alloc in graph
// capture + spill VMEM corrupting hand-counted vmcnt => container failure.
// 512-thr blocks (2 waves/SIMD, 256-VGPR cap) are structurally immune.
// Changes vs R8 (passed, 2.81us/step):
//  - 128 blocks x 512 threads (8 waves = 4 N-tiles x 2 K-halves), 64
//    h-cols/block, 16 blocks/XCD: rendezvous span 32 -> 16.
//  - SINGLE-POLLER: only wave 0 polls the flag line; waves 1-7 released
//    by a second __syncthreads. Pollers per line: 128 waves -> 16.
//  - dense 64B flag line (16 words), one coalesced wave-load per poll.
//  - out-store BEFORE the pre-flag drain (ack overlaps h-store ack).
//  - x-waves (slot-0, waves 4-5): explicit vmcnt(0) on xcur at step TOP
//    (they no longer pass the poll's waits); rest of the 1-step-ahead
//    x register pipeline as in R8, counts re-audited.
// Probe/symmetry/fallback (sc0 sc1 L3 protocol) carried over; NSLOT=16.

#define B_    32
#define T_    1000
#define D_    64
#define H_    1024
#define GRID  128
#define NTHR  512
#define LRATE 0.9f
#define NSLOT 16

#define ROWS  5              // 4 batch rows + 1 zero row (A rows 4..15)
#define RLEN  1088           // K extent: 1024 h + 64 x
#define BUFE  (ROWS * RLEN)  // 5440 bf16 per buffer

// ws layout (harness memsets ws each dispatch):
//   [0,1024)        device barrier arrive flags (128 ints used)
//   [1024,1056)     per-XCD block counters (8 ints)
//   [1056,1060)     badflag (probe verdict)
//   [8192,24576)    probe region: (g*16+slot)*128B {data[2] @+0, flag @+64}
//   [40960,43008)   per-group flag lines: 16 ints dense, 256B stride
//   [73728,335872)  per-group h buffers: 2*5440*2B, stride 32768
#define OFF_CNT      1024
#define OFF_BAD      1056
#define OFF_PROBE    8192
#define PROBE_STRIDE 128
#define OFF_FLAGS    40960
#define FLAG_STRIDE  256
#define OFF_HB       73728
#define HB_STRIDE    32768

#define DYN_LDS      (88 * 1024)   // + ~8.3KB static -> 1 block/CU

typedef __bf16 bf16_t;
typedef __bf16 bf16x8 __attribute__((ext_vector_type(8)));
typedef float  f32x4  __attribute__((ext_vector_type(4)));
typedef float  f32x2  __attribute__((ext_vector_type(2)));
typedef unsigned uint4v __attribute__((ext_vector_type(4)));

__device__ __forceinline__ unsigned pack_bf16(float a, float b) {
    unsigned short lo = __builtin_bit_cast(unsigned short, (bf16_t)a);
    unsigned short hi = __builtin_bit_cast(unsigned short, (bf16_t)b);
    return (unsigned)lo | ((unsigned)hi << 16);
}

// Device-wide barrier with release/acquire agent fences (wbl2 / inv).
__device__ __forceinline__ void device_barrier(int* arrive, int bid, int tid, int target) {
    __builtin_amdgcn_fence(__ATOMIC_RELEASE, "agent");
    __syncthreads();
    if (tid < 64) {
        if (tid == 0)
            __hip_atomic_store(&arrive[bid], target, __ATOMIC_RELAXED, __HIP_MEMORY_SCOPE_AGENT);
        for (;;) {
            int v0 = __hip_atomic_load(&arrive[tid],      __ATOMIC_RELAXED, __HIP_MEMORY_SCOPE_AGENT);
            int v1 = __hip_atomic_load(&arrive[tid + 64], __ATOMIC_RELAXED, __HIP_MEMORY_SCOPE_AGENT);
            if (__all((v0 >= target) & (v1 >= target))) break;
            __builtin_amdgcn_s_sleep(1);
        }
    }
    __syncthreads();
    __builtin_amdgcn_fence(__ATOMIC_ACQUIRE, "agent");
}

// LOCAL=true : plain store (write-through L1 -> XCD L2) + sc0 load (L1
//              bypass, reads XCD L2). Probe-validated before use.
// LOCAL=false: sc0 sc1 both ways (L3 coherence point) - R3's protocol.
template<bool LOCAL>
__device__ __forceinline__ void ld16(uint4v& r, const bf16_t* p) {
    if constexpr (LOCAL)
        asm volatile("global_load_dwordx4 %0, %1, off sc0" : "=&v"(r) : "v"(p) : "memory");
    else
        asm volatile("global_load_dwordx4 %0, %1, off sc0 sc1" : "=&v"(r) : "v"(p) : "memory");
}
template<bool LOCAL>
__device__ __forceinline__ void st32(void* p, unsigned v) {
    if constexpr (LOCAL)
        asm volatile("global_store_dword %0, %1, off" :: "v"(p), "v"(v) : "memory");
    else
        asm volatile("global_store_dword %0, %1, off sc0 sc1" :: "v"(p), "v"(v) : "memory");
}
template<bool LOCAL>
__device__ __forceinline__ int ldflag(const int* p) {
    int v;
    if constexpr (LOCAL)
        asm volatile("global_load_dword %0, %1, off sc0\n\ts_waitcnt vmcnt(0)"
                     : "=&v"(v) : "v"(p) : "memory");
    else
        asm volatile("global_load_dword %0, %1, off sc0 sc1\n\ts_waitcnt vmcnt(0)"
                     : "=&v"(v) : "v"(p) : "memory");
    return v;
}

template<bool LOCAL>
__device__ __forceinline__ void scan_loop(
    uint4v (&breg)[17],
    const bf16_t* Ab0, const bf16_t* Ab1,
    bf16_t* buf0, bf16_t* buf1,
    int* flags, int slot, int h0,
    f32x2 xcur,              // x_{t+1} data (preloaded slice 1; completed)
    const float* xq0,        // this thread's x pointer for slice t=2
    int xb, int xd,
    float* outp, float bias_c,
    float* lds, int tid, int lane, int wv)
{
    const int quad = lane >> 4;
    const int mcol = lane & 15;
    const bool isfin = (tid < 256);     // waves 0-3
    const int fb  = tid >> 6;           // finisher batch 0..3
    const int fc  = tid & 63;           // finisher col within block's 64
    const int fn  = fc >> 4, fcc = fc & 15;
    int*       myflag = flags + slot;           // dense: one int per slot
    const int* pollp  = flags + (lane & 15);    // 16 flags in one 64B line
    const bool isx    = (slot == 0) && (wv == 4 || wv == 5);  // wave-uniform
    const bool ispoll = (wv == 0);
    const float* xq = xq0;
    float hp = 0.f;

    #pragma unroll 1
    for (int t = 0; t < T_; ++t) {
        const bf16_t* Ab   = (t & 1) ? Ab1 : Ab0;
        bf16_t*       nxtb = (t & 1) ? buf0 : buf1;

        // TOP: store x_{t+1} (value loaded last step). x-waves no longer
        // pass the poll's waits, so complete the load explicitly here (it
        // was issued ~a full step ago; this wait is ~free). Only the
        // x-load can be outstanding for these waves at this point.
        if (isx && (t + 1) < T_) {
            asm volatile("s_waitcnt vmcnt(0)" : "+v"(xcur) :: "memory");
            unsigned pk = pack_bf16(xcur[0], xcur[1]);
            st32<LOCAL>(nxtb + xb * RLEN + H_ + xd, pk);
        }

        // A-fragments: 17 back-to-back 16B loads -> one L2 (LOCAL) / L3 RT.
        uint4v a0,a1,a2,a3,a4,a5,a6,a7,a8,a9,a10,a11,a12,a13,a14,a15,a16;
        ld16<LOCAL>(a0,  Ab +  0*32); ld16<LOCAL>(a1,  Ab +  1*32);
        ld16<LOCAL>(a2,  Ab +  2*32); ld16<LOCAL>(a3,  Ab +  3*32);
        ld16<LOCAL>(a4,  Ab +  4*32); ld16<LOCAL>(a5,  Ab +  5*32);
        ld16<LOCAL>(a6,  Ab +  6*32); ld16<LOCAL>(a7,  Ab +  7*32);
        ld16<LOCAL>(a8,  Ab +  8*32); ld16<LOCAL>(a9,  Ab +  9*32);
        ld16<LOCAL>(a10, Ab + 10*32); ld16<LOCAL>(a11, Ab + 11*32);
        ld16<LOCAL>(a12, Ab + 12*32); ld16<LOCAL>(a13, Ab + 13*32);
        ld16<LOCAL>(a14, Ab + 14*32); ld16<LOCAL>(a15, Ab + 15*32);
        ld16<LOCAL>(a16, Ab + 16*32);

        // x_{t+2} load, issued LAST so vmcnt(1) below waits exactly the
        // A-loads (in-order retirement) while x rides out under MFMA.
        const bool ldx = isx && (t + 2) < T_;
        if (ldx) {
            asm volatile("global_load_dwordx2 %0, %1, off"
                         : "=v"(xcur) : "v"(xq) : "memory");
            xq += D_;
        }

        #define AWAIT(N) asm volatile("s_waitcnt vmcnt(" #N ")" \
            : "+v"(a0),"+v"(a1),"+v"(a2),"+v"(a3),"+v"(a4),"+v"(a5), \
              "+v"(a6),"+v"(a7),"+v"(a8),"+v"(a9),"+v"(a10),"+v"(a11), \
              "+v"(a12),"+v"(a13),"+v"(a14),"+v"(a15),"+v"(a16) :: "memory")
        if (ldx) { AWAIT(1); } else { AWAIT(0); }
        #undef AWAIT

        // 17 MFMA, 4 interleaved accumulator chains.
        f32x4 acc0 = {0.f,0.f,0.f,0.f}, acc1 = acc0, acc2 = acc0, acc3 = acc0;
        #define AM(reg, idx, acc) \
            acc = __builtin_amdgcn_mfma_f32_16x16x32_bf16( \
                __builtin_bit_cast(bf16x8, reg), \
                __builtin_bit_cast(bf16x8, breg[idx]), acc, 0, 0, 0);
        AM(a0,0,acc0)   AM(a1,1,acc1)   AM(a2,2,acc2)   AM(a3,3,acc3)
        AM(a4,4,acc0)   AM(a5,5,acc1)   AM(a6,6,acc2)   AM(a7,7,acc3)
        AM(a8,8,acc0)   AM(a9,9,acc1)   AM(a10,10,acc2) AM(a11,11,acc3)
        AM(a12,12,acc0) AM(a13,13,acc1) AM(a14,14,acc2) AM(a15,15,acc3)
        AM(a16,16,acc0)
        #undef AM
        f32x4 acc = (acc0 + acc1) + (acc2 + acc3);

        // Cross-wave K-half reduce via LDS. C/D: col=lane&15, row=quad*4+i.
        #pragma unroll
        for (int i = 0; i < 4; ++i)
            lds[wv * 256 + (quad * 4 + i) * 16 + mcol] = acc[i];
        __syncthreads();

        float hn = 0.f;
        if (isfin) {
            // wave (n_=fn,kh) = region fn*2+kh; sum the two K-halves
            float s  = lds[(fn * 2)     * 256 + fb * 16 + fcc]
                     + lds[(fn * 2 + 1) * 256 + fb * 16 + fcc];
            float u  = s + bias_c;
            // tanh(u) = 1 - 2/(e^{2u}+1); saturates correctly at +-inf.
            float ex = __expf(2.f * u);
            float th = 1.f - 2.f * __builtin_amdgcn_rcpf(ex + 1.f);
            hn = (1.f - LRATE) * hp + LRATE * th;
            hp = hn;
            unsigned hbits = (unsigned)__builtin_bit_cast(unsigned short, (bf16_t)hn);
            unsigned hi    = __shfl_down(hbits, 1);
            if (!(tid & 1))
                st32<LOCAL>(nxtb + fb * RLEN + h0 + fc, hbits | (hi << 16));
        }

        if (t + 1 < T_) {
            // out-store BEFORE the drain: its L2 ack overlaps the h-store
            // ack in one window and stays off the rendezvous path.
            if (isfin) outp[(size_t)t * H_] = hn;
            // Drain h/out-store acks. x-waves with an in-flight x load
            // skip (their x-store retired at the A-wait vmcnt(1)).
            if (!ldx) asm volatile("s_waitcnt vmcnt(0)" ::: "memory");
            __syncthreads();
            if (tid == 0)
                st32<LOCAL>(myflag, (unsigned)(t + 1));
            if (ispoll) {
                // SINGLE-POLLER: 2-deep pipelined poll by wave 0 only.
                // Wave 0 outstanding before PLD: flag store (tid 0) only;
                // vmcnt(1) retires it plus the checked load. In-order.
                const int target = t + 1;
                int v0 = 0, v1 = 0;
                #define PLD(r) do { if constexpr (LOCAL) \
                        asm volatile("global_load_dword %0, %1, off sc0" \
                                     : "=v"(r) : "v"(pollp) : "memory"); \
                    else \
                        asm volatile("global_load_dword %0, %1, off sc0 sc1" \
                                     : "=v"(r) : "v"(pollp) : "memory"); } while (0)
                PLD(v0); PLD(v1);
                for (;;) {
                    asm volatile("s_waitcnt vmcnt(1)" : "+v"(v0) :: "memory");
                    if (__all(v0 >= target)) break;
                    PLD(v0);
                    asm volatile("s_waitcnt vmcnt(1)" : "+v"(v1) :: "memory");
                    if (__all(v1 >= target)) break;
                    PLD(v1);
                }
                #undef PLD
            }
            // Release: all waves wait for wave 0's poll exit.
            __syncthreads();
            // Re-def xcur: x-wave consumers are ordered after this point.
            asm volatile("" : "+v"(xcur) :: );
        } else {
            if (isfin) outp[(size_t)t * H_] = hn;
        }
    }
}

__global__ __launch_bounds__(NTHR) void esn_scan(
    const float* __restrict__ x,     // [B, T, D]
    const float* __restrict__ Win,   // [H, D]
    const float* __restrict__ bias,  // [H]
    const float* __restrict__ W,     // [H, H]
    float* __restrict__ out,         // [B, T, H]
    unsigned char* wsb)
{
    extern __shared__ unsigned char dynsmem[];   // occupancy ballast (88KB)
    __shared__ float lds[8 * 256];               // 8KB cross-wave reduce
    __shared__ int slot_sh;
    (void)dynsmem;

    int* darr = (int*)wsb;
    int* cnt  = (int*)(wsb + OFF_CNT);
    int* badp = (int*)(wsb + OFF_BAD);

    unsigned xcd;
    asm volatile("s_getreg_b32 %0, hwreg(HW_REG_XCC_ID)" : "=s"(xcd));
    xcd &= 7;

    const int tid  = threadIdx.x;
    const int bid  = blockIdx.x;
    const int lane = tid & 63;
    const int wv   = tid >> 6;

    if (tid == 0) slot_sh = atomicAdd(&cnt[xcd], 1);
    __syncthreads();
    const int slot_raw = slot_sh;

    device_barrier(darr, bid, tid, 1);

    // Symmetry: did every XCD get exactly 16 blocks? (Deterministic when
    // the big-LDS coop launch succeeded: 1 block/CU, 128 blocks spread.)
    bool sym;
    {
        int c = __hip_atomic_load(&cnt[lane & 7], __ATOMIC_RELAXED, __HIP_MEMORY_SCOPE_AGENT);
        sym = __all(c == NSLOT);
    }
    const int g  = sym ? (int)xcd : (bid & 7);
    const int s  = sym ? slot_raw : (bid >> 3);
    const int h0 = s * 64;

    // ---- LOCAL-coherence probe (only when placement is symmetric) ----
    if (sym && tid == 0) {
        unsigned* pd = (unsigned*)(wsb + OFF_PROBE + ((size_t)g * NSLOT + s) * PROBE_STRIDE);
        unsigned* pf = pd + 16;   // +64B
        unsigned* nd = (unsigned*)(wsb + OFF_PROBE + ((size_t)g * NSLOT + ((s + 1) & 15)) * PROBE_STRIDE);
        unsigned* nf = nd + 16;
        int bad = 0;
        for (int round = 1; round <= 2 && !bad; ++round) {
            unsigned val = 0xA5000000u + ((unsigned)round << 16) + (unsigned)s;
            st32<true>(pd + (round & 1), val);
            asm volatile("s_waitcnt vmcnt(0)" ::: "memory");
            st32<true>(pf, (unsigned)round);
            unsigned fv = 0; int iters = 0;
            for (;;) {
                fv = (unsigned)ldflag<true>((const int*)nf);
                if (fv >= (unsigned)round) break;
                if (++iters > 8192) { bad = 1; break; }
            }
            if (!bad) {
                unsigned dv = (unsigned)ldflag<true>((const int*)(nd + (round & 1)));
                unsigned expect = 0xA5000000u + ((unsigned)round << 16) + (unsigned)((s + 1) & 15);
                if (dv != expect) bad = 1;
            }
        }
        if (bad) atomicOr(badp, 1);
    }

    device_barrier(darr, bid, tid, 2);

    int badv = __hip_atomic_load(badp, __ATOMIC_RELAXED, __HIP_MEMORY_SCOPE_AGENT);
    const bool local = sym && (badv == 0);

    int*    flags = (int*)(wsb + OFF_FLAGS + (size_t)g * FLAG_STRIDE);
    bf16_t* hb    = (bf16_t*)(wsb + OFF_HB + (size_t)g * HB_STRIDE);
    bf16_t* buf0  = hb;
    bf16_t* buf1  = hb + BUFE;

    // ---------------- init ----------------
    // Zero buf0 h-region (rows 0-3, k<1024) + zero-row 4 of BOTH buffers.
    {
        unsigned* hb32 = (unsigned*)hb;              // u32 view, row stride 544
        unsigned gi = (unsigned)s * NTHR + tid;      // 0..8191 across group
        if (gi < 2048)            hb32[(gi >> 9) * 544 + (gi & 511)] = 0;
        else if (gi < 2592)       hb32[4 * 544 + (gi - 2048)] = 0;
        else if (gi < 3136)       hb32[2720 + 4 * 544 + (gi - 2592)] = 0;
        if (s == 0 && tid < 256) {   // stage x_0 into buf0 x-region
            int b = tid >> 6, d = tid & 63;
            float v = x[(size_t)(4 * g + b) * (T_ * D_) + d];
            hb[b * RLEN + H_ + d] = (bf16_t)v;
        }
    }

    // B-fragments: W rows [h0,h0+64) (+ Win for k>=1024), bf16, registers.
    const int n_   = wv >> 1;         // N-tile 0..3 (16 cols each)
    const int kh   = wv & 1;          // K half [kh*544, kh*544+544)
    const int quad = lane >> 4;
    const int mcol = lane & 15;
    const int col  = h0 + n_ * 16 + mcol;

    uint4v breg[17];
    for (int kc = 0; kc < 17; ++kc) {
        int kb = kh * 544 + kc * 32 + quad * 8;
        float v[8];
        #pragma unroll
        for (int j = 0; j < 8; ++j) {
            int k = kb + j;
            v[j] = (k < H_) ? W[(size_t)col * H_ + k]
                            : Win[col * D_ + (k - H_)];
        }
        uint4v p;
        p[0] = pack_bf16(v[0], v[1]); p[1] = pack_bf16(v[2], v[3]);
        p[2] = pack_bf16(v[4], v[5]); p[3] = pack_bf16(v[6], v[7]);
        breg[kc] = p;
    }

    // A-fragment base: row = batch (lane&15), rows >=4 clamp to zero-row 4.
    const int rr   = (mcol < 4) ? mcol : 4;
    const int aoff = rr * RLEN + kh * 544 + quad * 8;
    const bf16_t* Ab0 = buf0 + aoff;
    const bf16_t* Ab1 = buf1 + aoff;

    // Finisher state (waves 0-3): one (batch, col) per thread.
    const int fb = tid >> 6;          // batch 0..3
    const int fc = tid & 63;          // col within block's 64
    const float bias_c = bias[h0 + fc];
    float* outp = out + (size_t)(4 * g + fb) * (T_ * H_) + h0 + fc;

    // x-pipeline state (slot-0 block, waves 4-5): 2 floats/thread/step.
    const int t2 = tid & 127;         // 0..127 within waves 4-5
    const int xb = t2 >> 5, xd = (t2 & 31) * 2;
    const float* xp = x + (size_t)(4 * g + xb) * (T_ * D_) + D_ + xd; // t=1

    // Preload x slice t=1 into the pipeline register.
    f32x2 xcur = {0.f, 0.f};
    if (s == 0 && tid >= 256 && tid < 384) {
        asm volatile("global_load_dwordx2 %0, %1, off" : "=v"(xcur) : "v"(xp) : "memory");
        asm volatile("s_waitcnt vmcnt(0)" : "+v"(xcur) :: "memory");
    }

    device_barrier(darr, bid, tid, 3);   // flushes init stores (wbl2)

    // ---------------- scan ----------------
    if (local)
        scan_loop<true >(breg, Ab0, Ab1, buf0, buf1, flags, s, h0,
                         xcur, xp + D_, xb, xd, outp, bias_c, lds, tid, lane, wv);
    else
        scan_loop<false>(breg, Ab0, Ab1, buf0, buf1, flags, s, h0,
                         xcur, xp + D_, xb, xd, outp, bias_c, lds, tid, lane, wv);
}

extern "C" void kernel_launch(void* const* d_in, const int* in_sizes, int n_in,
                              void* d_out, int out_size, void* d_ws, size_t ws_size,
                              hipStream_t stream) {
    (void)in_sizes; (void)n_in; (void)out_size; (void)ws_size;
    const float* x    = (const float*)d_in[0];
    const float* Win  = (const float*)d_in[1];
    const float* bias = (const float*)d_in[2];
    const float* W    = (const float*)d_in[3];
    float*       out  = (float*)d_out;
    void*        ws   = d_ws;

    static int attr_ok = -1;
    if (attr_ok < 0) {
        hipError_t ae = hipFuncSetAttribute((const void*)esn_scan,
                            hipFuncAttributeMaxDynamicSharedMemorySize, DYN_LDS);
        attr_ok = (ae == hipSuccess) ? 1 : 0;
    }

    void* args[] = { (void*)&x, (void*)&Win, (void*)&bias, (void*)&W, (void*)&out, (void*)&ws };
    hipError_t e = hipErrorUnknown;
    if (attr_ok == 1)
        e = hipLaunchCooperativeKernel((const void*)esn_scan, dim3(GRID), dim3(NTHR),
                                       args, DYN_LDS, stream);
    if (e != hipSuccess)
        e = hipLaunchCooperativeKernel((const void*)esn_scan, dim3(GRID), dim3(NTHR),
                                       args, 0, stream);
    if (e != hipSuccess)
        hipLaunchKernelGGL(esn_scan, dim3(GRID), dim3(NTHR), 0, stream,
                           x, Win, bias, W, out, (unsigned char*)ws);
}

// Round 8
// 2438.945 us; speedup vs baseline: 1.4581x; 1.4581x over previous
//
#include <hip/hip_runtime.h>
#include <hip/hip_bf16.h>

// ESN scan: h_{t+1} = 0.1*h_t + 0.9*tanh(x_t @ Win^T + b + h_t @ W^T)
// B=32, T=1000, D=64, H=1024.
//
// R11: LDS-staged A + single-poller (R8 base structure, which passed at
// 2.81us/step; R10's 128x512 restructure regressed and is abandoned).
// Theory: step time is dominated by L2 queuing on (a) the A-broadcast
// (every wave re-reads its K-slice of h from L2 each step: ~15-20K line
// reads/XCD/step into a 10KB region) and (b) 128 waves polling one flag
// line. Fixes:
//  - Each block stages h||x rows 0-3 (8.7KB) global->LDS once per step
//    with 3 coalesced 16B loads/thread (sc0: L1 would serve stale clean
//    lines), then reads MFMA A-fragments from LDS (row 4 = resident zero
//    row; +16B row pad keeps 16B alignment, worst 4-way bank conflict).
//    5-10x cut in per-step L2 read pressure.
//  - Wave 0 is the only L2 poller (2-deep pipelined poll, counts audited);
//    waves 1-3 spin on an LDS release word (no L2 traffic, no extra
//    __syncthreads - R10's release barrier mistake avoided).
// Everything else (grouping, probe, fallback sc0 sc1 protocol, x register
// pipeline, fast tanh, launch ladder) identical to R8.

#define B_    32
#define T_    1000
#define D_    64
#define H_    1024
#define GRID  256
#define NTHR  256
#define LRATE 0.9f
#define NSLOT 32

#define RLEN  1088           // K extent: 1024 h + 64 x
#define BUFE  (4 * RLEN)     // 4 batch rows per buffer (no global zero row)
#define LSTR  2192           // LDS A row stride bytes (2176 data + 16 pad)

// ws layout (harness memsets ws each dispatch):
//   [0,1024)        device barrier arrive flags (256 ints)
//   [1024,1056)     per-XCD block counters (8 ints)
//   [1056,1060)     badflag (probe verdict)
//   [8192,40960)    probe region: (g*32+slot)*128B {data[2] @+0, flag @+64}
//   [40960,43008)   per-group flag lines: 32 ints dense, 256B stride
//   [73728,335872)  per-group h buffers: 2*4352*2B, stride 32768
#define OFF_CNT      1024
#define OFF_BAD      1056
#define OFF_PROBE    8192
#define PROBE_STRIDE 128
#define OFF_FLAGS    40960
#define FLAG_STRIDE  256
#define OFF_HB       73728
#define HB_STRIDE    32768

#define DYN_LDS      (88 * 1024)   // + ~15KB static -> 1 block/CU

typedef __bf16 bf16_t;
typedef __bf16 bf16x8 __attribute__((ext_vector_type(8)));
typedef float  f32x4  __attribute__((ext_vector_type(4)));
typedef float  f32x2  __attribute__((ext_vector_type(2)));
typedef unsigned uint4v __attribute__((ext_vector_type(4)));

__device__ __forceinline__ unsigned pack_bf16(float a, float b) {
    unsigned short lo = __builtin_bit_cast(unsigned short, (bf16_t)a);
    unsigned short hi = __builtin_bit_cast(unsigned short, (bf16_t)b);
    return (unsigned)lo | ((unsigned)hi << 16);
}

// Device-wide barrier with release/acquire agent fences (wbl2 / inv).
__device__ __forceinline__ void device_barrier(int* arrive, int bid, int tid, int target) {
    __builtin_amdgcn_fence(__ATOMIC_RELEASE, "agent");
    __syncthreads();
    if (tid < 64) {
        if (tid == 0)
            __hip_atomic_store(&arrive[bid], target, __ATOMIC_RELAXED, __HIP_MEMORY_SCOPE_AGENT);
        for (;;) {
            int v0 = __hip_atomic_load(&arrive[tid],       __ATOMIC_RELAXED, __HIP_MEMORY_SCOPE_AGENT);
            int v1 = __hip_atomic_load(&arrive[tid + 64],  __ATOMIC_RELAXED, __HIP_MEMORY_SCOPE_AGENT);
            int v2 = __hip_atomic_load(&arrive[tid + 128], __ATOMIC_RELAXED, __HIP_MEMORY_SCOPE_AGENT);
            int v3 = __hip_atomic_load(&arrive[tid + 192], __ATOMIC_RELAXED, __HIP_MEMORY_SCOPE_AGENT);
            if (__all((v0 >= target) & (v1 >= target) & (v2 >= target) & (v3 >= target))) break;
            __builtin_amdgcn_s_sleep(1);
        }
    }
    __syncthreads();
    __builtin_amdgcn_fence(__ATOMIC_ACQUIRE, "agent");
}

// LOCAL=true : plain store (write-through L1 -> XCD L2) + sc0 load (L1
//              bypass, reads XCD L2). Probe-validated before use.
// LOCAL=false: sc0 sc1 both ways (L3 coherence point) - R3's protocol.
template<bool LOCAL>
__device__ __forceinline__ void ld16(uint4v& r, const bf16_t* p) {
    if constexpr (LOCAL)
        asm volatile("global_load_dwordx4 %0, %1, off sc0" : "=&v"(r) : "v"(p) : "memory");
    else
        asm volatile("global_load_dwordx4 %0, %1, off sc0 sc1" : "=&v"(r) : "v"(p) : "memory");
}
template<bool LOCAL>
__device__ __forceinline__ void st32(void* p, unsigned v) {
    if constexpr (LOCAL)
        asm volatile("global_store_dword %0, %1, off" :: "v"(p), "v"(v) : "memory");
    else
        asm volatile("global_store_dword %0, %1, off sc0 sc1" :: "v"(p), "v"(v) : "memory");
}
template<bool LOCAL>
__device__ __forceinline__ int ldflag(const int* p) {
    int v;
    if constexpr (LOCAL)
        asm volatile("global_load_dword %0, %1, off sc0\n\ts_waitcnt vmcnt(0)"
                     : "=&v"(v) : "v"(p) : "memory");
    else
        asm volatile("global_load_dword %0, %1, off sc0 sc1\n\ts_waitcnt vmcnt(0)"
                     : "=&v"(v) : "v"(p) : "memory");
    return v;
}

template<bool LOCAL>
__device__ __forceinline__ void scan_loop(
    uint4v (&breg)[17],
    bf16_t* buf0, bf16_t* buf1,
    int* flags, int slot, int h0,
    f32x2 xcur,              // x_{t+1} data (preloaded slice 1; completed)
    const float* xq0,        // this thread's x pointer for slice t=2
    int xb, int xd,
    float* outp, float bias_c,
    unsigned char* ldsA, float* ldsR, int* rel,
    int tid, int lane, int wv)
{
    const int quad = lane >> 4;
    const int mcol = lane & 15;
    const int kh   = wv >> 1;          // K half
    const int rr   = (mcol < 4) ? mcol : 4;  // A row (4 = LDS zero row)
    const int fb   = (tid >> 5) & 3;
    const int fcw  = tid & 31;
    const int fn   = fcw >> 4, fcc = fcw & 15;
    const int srow = tid >> 6;         // stage row 0..3 (one wave per row)
    const int sl   = tid & 63;         // stage lane -> 16B chunk ids
    int*       myflag = flags + slot;           // dense: one int per slot
    const int* pollp  = flags + (lane & 31);    // 32 flags in one 128B line
    const bool isx = (slot == 0) && (wv >= 2);  // wave-uniform
    const float* xq = xq0;
    float hp = 0.f;
    // MFMA A-fragment base in LDS (16B aligned: LSTR,1088,16 all %16==0)
    const uint4v* ap = (const uint4v*)(ldsA + rr * LSTR + kh * 1088 + quad * 16);

    #pragma unroll 1
    for (int t = 0; t < T_; ++t) {
        const bf16_t* cur  = (t & 1) ? buf1 : buf0;
        bf16_t*       nxtb = (t & 1) ? buf0 : buf1;

        // TOP: store x_{t+1} (loaded >=1 step ago; complete it explicitly -
        // x-waves don't pass the poll's waits). Only the x-load can be
        // outstanding for these waves here.
        if (isx && (t + 1) < T_) {
            asm volatile("s_waitcnt vmcnt(0)" : "+v"(xcur) :: "memory");
            unsigned pk = pack_bf16(xcur[0], xcur[1]);
            st32<LOCAL>(nxtb + xb * RLEN + H_ + xd, pk);
        }

        // STAGE: cooperatively load rows 0-3 of cur (h||x, 8.7KB) -> LDS.
        // Per thread: chunks sl, sl+64, 128+(sl&7) of its row (the third is
        // 8x duplicated across lanes - benign identical writes, keeps vmcnt
        // wave-uniform with zero divergence).
        uint4v s0, s1, s2;
        {
            const bf16_t* sp = cur + srow * RLEN;
            ld16<LOCAL>(s0, sp + sl * 8);
            ld16<LOCAL>(s1, sp + sl * 8 + 512);
            ld16<LOCAL>(s2, sp + (128 + (sl & 7)) * 8);
        }

        // x_{t+2} load, issued LAST so vmcnt(1) below waits exactly the
        // stage loads (+retired x-store) while x rides out under MFMA.
        const bool ldx = isx && (t + 2) < T_;
        if (ldx) {
            asm volatile("global_load_dwordx2 %0, %1, off"
                         : "=v"(xcur) : "v"(xq) : "memory");
            xq += D_;
        }
        if (ldx)
            asm volatile("s_waitcnt vmcnt(1)"
                         : "+v"(s0), "+v"(s1), "+v"(s2) :: "memory");
        else
            asm volatile("s_waitcnt vmcnt(0)"
                         : "+v"(s0), "+v"(s1), "+v"(s2) :: "memory");

        *(uint4v*)(ldsA + srow * LSTR + sl * 16)              = s0;
        *(uint4v*)(ldsA + srow * LSTR + (sl + 64) * 16)       = s1;
        *(uint4v*)(ldsA + srow * LSTR + (128 + (sl & 7)) * 16) = s2;
        __syncthreads();

        // 17 MFMA from LDS A-fragments, 4 interleaved accumulator chains.
        f32x4 acc[4] = {{0.f,0.f,0.f,0.f},{0.f,0.f,0.f,0.f},
                        {0.f,0.f,0.f,0.f},{0.f,0.f,0.f,0.f}};
        #pragma unroll
        for (int kc = 0; kc < 17; ++kc) {
            uint4v a = ap[kc * 4];        // kc*64B
            acc[kc & 3] = __builtin_amdgcn_mfma_f32_16x16x32_bf16(
                __builtin_bit_cast(bf16x8, a),
                __builtin_bit_cast(bf16x8, breg[kc]), acc[kc & 3], 0, 0, 0);
        }
        f32x4 accs = (acc[0] + acc[1]) + (acc[2] + acc[3]);

        // Cross-wave K-half reduce via LDS. C/D: col=lane&15, row=quad*4+i.
        #pragma unroll
        for (int i = 0; i < 4; ++i)
            ldsR[wv * 256 + (quad * 4 + i) * 16 + mcol] = accs[i];
        __syncthreads();

        float hn = 0.f;
        if (tid < 128) {
            // wave (n_=fn,kh=0) = region fn; wave (n_=fn,kh=1) = region fn+2
            float s  = ldsR[fn * 256 + fb * 16 + fcc]
                     + ldsR[(fn + 2) * 256 + fb * 16 + fcc];
            float u  = s + bias_c;
            // tanh(u) = 1 - 2/(e^{2u}+1); saturates correctly at +-inf.
            float ex = __expf(2.f * u);
            float th = 1.f - 2.f * __builtin_amdgcn_rcpf(ex + 1.f);
            hn = (1.f - LRATE) * hp + LRATE * th;
            hp = hn;
            unsigned hbits = (unsigned)__builtin_bit_cast(unsigned short, (bf16_t)hn);
            unsigned hi    = __shfl_down(hbits, 1);
            if (!(tid & 1))
                st32<LOCAL>(nxtb + fb * RLEN + h0 + fcw, hbits | (hi << 16));
        }

        if (t + 1 < T_) {
            // out-store BEFORE the drain: ack overlaps h-store ack.
            if (tid < 128) outp[(size_t)t * H_] = hn;
            // Drain h/out acks. x-waves with in-flight x load skip (their
            // x-store retired at the stage vmcnt(1)).
            if (!ldx) asm volatile("s_waitcnt vmcnt(0)" ::: "memory");
            __syncthreads();
            if (tid == 0)
                st32<LOCAL>(myflag, (unsigned)(t + 1));
            const int target = t + 1;
            if (wv == 0) {
                // SINGLE L2 POLLER: 2-deep pipelined poll (counts: flag
                // store + p0 + p1 -> vmcnt(1) retires through p0; audited).
                int v0 = 0, v1 = 0;
                #define PLD(r) do { if constexpr (LOCAL) \
                        asm volatile("global_load_dword %0, %1, off sc0" \
                                     : "=v"(r) : "v"(pollp) : "memory"); \
                    else \
                        asm volatile("global_load_dword %0, %1, off sc0 sc1" \
                                     : "=v"(r) : "v"(pollp) : "memory"); } while (0)
                PLD(v0); PLD(v1);
                for (;;) {
                    asm volatile("s_waitcnt vmcnt(1)" : "+v"(v0) :: "memory");
                    if (__all(v0 >= target)) break;
                    PLD(v0);
                    asm volatile("s_waitcnt vmcnt(1)" : "+v"(v1) :: "memory");
                    if (__all(v1 >= target)) break;
                    PLD(v1);
                }
                #undef PLD
                if (tid == 0)
                    __hip_atomic_store(rel, target, __ATOMIC_RELAXED,
                                       __HIP_MEMORY_SCOPE_WORKGROUP);
            } else {
                // LDS release spin: no L2 traffic, ~30cy/iter.
                while (__hip_atomic_load(rel, __ATOMIC_RELAXED,
                                         __HIP_MEMORY_SCOPE_WORKGROUP) < target) {}
            }
            // Re-def xcur: consumers are ordered after this point.
            asm volatile("" : "+v"(xcur) :: );
        } else {
            if (tid < 128) outp[(size_t)t * H_] = hn;
        }
    }
}

__global__ __launch_bounds__(NTHR, 1) void esn_scan(
    const float* __restrict__ x,     // [B, T, D]
    const float* __restrict__ Win,   // [H, D]
    const float* __restrict__ bias,  // [H]
    const float* __restrict__ W,     // [H, H]
    float* __restrict__ out,         // [B, T, H]
    unsigned char* wsb)
{
    extern __shared__ unsigned char dynsmem[];   // occupancy ballast (88KB)
    __shared__ __align__(16) unsigned char ldsA[5 * LSTR]; // A stage + zero row
    __shared__ float ldsR[1024];                 // cross-wave reduce
    __shared__ int   rel;                        // poll release word
    __shared__ int   slot_sh;
    (void)dynsmem;

    int* darr = (int*)wsb;
    int* cnt  = (int*)(wsb + OFF_CNT);
    int* badp = (int*)(wsb + OFF_BAD);

    unsigned xcd;
    asm volatile("s_getreg_b32 %0, hwreg(HW_REG_XCC_ID)" : "=s"(xcd));
    xcd &= 7;

    const int tid  = threadIdx.x;
    const int bid  = blockIdx.x;
    const int lane = tid & 63;
    const int wv   = tid >> 6;

    if (tid == 0) slot_sh = atomicAdd(&cnt[xcd], 1);
    __syncthreads();
    const int slot_raw = slot_sh;

    device_barrier(darr, bid, tid, 1);

    // Symmetry: did every XCD get exactly 32 blocks?
    bool sym;
    {
        int c = __hip_atomic_load(&cnt[lane & 7], __ATOMIC_RELAXED, __HIP_MEMORY_SCOPE_AGENT);
        sym = __all(c == NSLOT);
    }
    const int g  = sym ? (int)xcd : (bid & 7);
    const int s  = sym ? slot_raw : (bid >> 3);
    const int h0 = s * 32;

    // ---- LOCAL-coherence probe (only when placement is symmetric) ----
    if (sym && tid == 0) {
        unsigned* pd = (unsigned*)(wsb + OFF_PROBE + ((size_t)g * NSLOT + s) * PROBE_STRIDE);
        unsigned* pf = pd + 16;   // +64B
        unsigned* nd = (unsigned*)(wsb + OFF_PROBE + ((size_t)g * NSLOT + ((s + 1) & 31)) * PROBE_STRIDE);
        unsigned* nf = nd + 16;
        int bad = 0;
        for (int round = 1; round <= 2 && !bad; ++round) {
            unsigned val = 0xA5000000u + ((unsigned)round << 16) + (unsigned)s;
            st32<true>(pd + (round & 1), val);
            asm volatile("s_waitcnt vmcnt(0)" ::: "memory");
            st32<true>(pf, (unsigned)round);
            unsigned fv = 0; int iters = 0;
            for (;;) {
                fv = (unsigned)ldflag<true>((const int*)nf);
                if (fv >= (unsigned)round) break;
                if (++iters > 8192) { bad = 1; break; }
            }
            if (!bad) {
                unsigned dv = (unsigned)ldflag<true>((const int*)(nd + (round & 1)));
                unsigned expect = 0xA5000000u + ((unsigned)round << 16) + (unsigned)((s + 1) & 31);
                if (dv != expect) bad = 1;
            }
        }
        if (bad) atomicOr(badp, 1);
    }

    device_barrier(darr, bid, tid, 2);

    int badv = __hip_atomic_load(badp, __ATOMIC_RELAXED, __HIP_MEMORY_SCOPE_AGENT);
    const bool local = sym && (badv == 0);

    int*    flags = (int*)(wsb + OFF_FLAGS + (size_t)g * FLAG_STRIDE);
    bf16_t* hb    = (bf16_t*)(wsb + OFF_HB + (size_t)g * HB_STRIDE);
    bf16_t* buf0  = hb;
    bf16_t* buf1  = hb + BUFE;

    // ---------------- init ----------------
    // Zero buf0 h-region rows 0-3 (buf1 fully written by step 0 producers;
    // the MFMA zero row now lives in LDS, not global).
    {
        unsigned* hb32 = (unsigned*)hb;          // u32 view, row stride 544
        unsigned gi = (unsigned)s * NTHR + tid;  // 0..8191 across group
        if (gi < 2048) hb32[(gi >> 9) * 544 + (gi & 511)] = 0;
        if (s == 0) {                            // stage x_0 into buf0
            int b = tid >> 6, d = tid & 63;
            float v = x[(size_t)(4 * g + b) * (T_ * D_) + d];
            hb[b * RLEN + H_ + d] = (bf16_t)v;
        }
    }
    // LDS init: zero row 4 of ldsA; release word = 0.
    {
        unsigned* za = (unsigned*)(ldsA + 4 * LSTR);
        for (int j = tid; j < LSTR / 4; j += NTHR) za[j] = 0;
        if (tid == 0) rel = 0;
    }

    // B-fragments: W rows [h0,h0+32) (+ Win for k>=1024), bf16, registers.
    const int n_   = wv & 1;          // N-tile (16 cols)
    const int kh   = wv >> 1;         // K half [kh*544, kh*544+544)
    const int quad = lane >> 4;
    const int mcol = lane & 15;
    const int col  = h0 + n_ * 16 + mcol;

    uint4v breg[17];
    for (int kc = 0; kc < 17; ++kc) {
        int kb = kh * 544 + kc * 32 + quad * 8;
        float v[8];
        #pragma unroll
        for (int j = 0; j < 8; ++j) {
            int k = kb + j;
            v[j] = (k < H_) ? W[(size_t)col * H_ + k]
                            : Win[col * D_ + (k - H_)];
        }
        uint4v p;
        p[0] = pack_bf16(v[0], v[1]); p[1] = pack_bf16(v[2], v[3]);
        p[2] = pack_bf16(v[4], v[5]); p[3] = pack_bf16(v[6], v[7]);
        breg[kc] = p;
    }

    // Finisher state (waves 0-1): one (batch, col) per thread.
    const int fb  = (tid >> 5) & 3;
    const int fcw = tid & 31;
    const float bias_c = bias[h0 + fcw];
    float* outp = out + (size_t)(4 * g + fb) * (T_ * H_) + h0 + fcw;

    // x-pipeline state (slot-0 block, waves 2-3): 2 floats/thread/step.
    const int t2 = tid & 127;
    const int xb = t2 >> 5, xd = (t2 & 31) * 2;
    const float* xp = x + (size_t)(4 * g + xb) * (T_ * D_) + D_ + xd; // t=1

    // Preload x slice t=1 into the pipeline register.
    f32x2 xcur = {0.f, 0.f};
    if (s == 0 && tid >= 128) {
        asm volatile("global_load_dwordx2 %0, %1, off" : "=v"(xcur) : "v"(xp) : "memory");
        asm volatile("s_waitcnt vmcnt(0)" : "+v"(xcur) :: "memory");
    }

    device_barrier(darr, bid, tid, 3);   // flushes init stores (wbl2)

    // ---------------- scan ----------------
    if (local)
        scan_loop<true >(breg, buf0, buf1, flags, s, h0,
                         xcur, xp + D_, xb, xd, outp, bias_c,
                         ldsA, ldsR, &rel, tid, lane, wv);
    else
        scan_loop<false>(breg, buf0, buf1, flags, s, h0,
                         xcur, xp + D_, xb, xd, outp, bias_c,
                         ldsA, ldsR, &rel, tid, lane, wv);
}

extern "C" void kernel_launch(void* const* d_in, const int* in_sizes, int n_in,
                              void* d_out, int out_size, void* d_ws, size_t ws_size,
                              hipStream_t stream) {
    (void)in_sizes; (void)n_in; (void)out_size; (void)ws_size;
    const float* x    = (const float*)d_in[0];
    const float* Win  = (const float*)d_in[1];
    const float* bias = (const float*)d_in[2];
    const float* W    = (const float*)d_in[3];
    float*       out  = (float*)d_out;
    void*        ws   = d_ws;

    static int attr_ok = -1;
    if (attr_ok < 0) {
        hipError_t ae = hipFuncSetAttribute((const void*)esn_scan,
                            hipFuncAttributeMaxDynamicSharedMemorySize, DYN_LDS);
        attr_ok = (ae == hipSuccess) ? 1 : 0;
    }

    void* args[] = { (void*)&x, (void*)&Win, (void*)&bias, (void*)&W, (void*)&out, (void*)&ws };
    hipError_t e = hipErrorUnknown;
    if (attr_ok == 1)
        e = hipLaunchCooperativeKernel((const void*)esn_scan, dim3(GRID), dim3(NTHR),
                                       args, DYN_LDS, stream);
    if (e != hipSuccess)
        e = hipLaunchCooperativeKernel((const void*)esn_scan, dim3(GRID), dim3(NTHR),
                                       args, 0, stream);
    if (e != hipSuccess)
        hipLaunchKernelGGL(esn_scan, dim3(GRID), dim3(NTHR), 0, stream,
                           x, Win, bias, W, out, (unsigned char*)ws);
}

// Round 12
// 2317.484 us; speedup vs baseline: 1.5345x; 1.0524x over previous
//
#include <hip/hip_runtime.h>
#include <hip/hip_bf16.h>

// ESN scan: h_{t+1} = 0.1*h_t + 0.9*tanh(x_t @ Win^T + b + h_t @ W^T)
// B=32, T=1000, D=64, H=1024.
//
// R15: revert to R11's verified flag protocol (2.34us/step) + audited
// protocol-neutral deltas. R13/R14 post-mortem: two numeric failures at
// two atomicity granularities => gfx950 vector loads are NOT snapshot-
// atomic; tag==t cannot soundly imply data-fresh within one load. The
// sound minimal protocol is R11's flag-then-stage. Deltas vs R11:
//  - x REMOVED from the published buffer: x is read-only input, needs no
//    protocol. Each wave pipelines xreg = x[4g+w][t][lane] one step ahead
//    in a register (reload issued post-stage -> full step of latency
//    cover) and converts it into the LDS x-columns during stage. Deletes
//    the slot-0 x-publish straggler and all vmcnt special cases (every
//    wait is plain vmcnt(0) except the audited 2-deep poll vmcnt(1)).
//  - out-store AFTER the flag publish (R11 had its L2 ack inside the
//    pre-flag drain; R8's placement was right).
//  - published h row = 1024 cols (stage: 2x16B loads/lane, was 3).
// Everything else (grouping, probe, sc0 sc1 fallback, LDS-staged A,
// single-poller + LDS release, fast tanh, launch ladder) = R11 verbatim.

#define B_    32
#define T_    1000
#define D_    64
#define H_    1024
#define GRID  256
#define NTHR  256
#define LRATE 0.9f
#define NSLOT 32

#define LSTR  2192           // LDS A row stride bytes (2176 data + 16 pad)
#define ROWE  1024           // published h row: 1024 bf16 (2048B)
#define BUFE  (4 * ROWE)     // 4 batch rows per buffer

// ws layout (harness memsets ws each dispatch; flags rely on this):
//   [0,1024)        device barrier arrive flags (256 ints)
//   [1024,1056)     per-XCD block counters (8 ints)
//   [1056,1060)     badflag (probe verdict)
//   [8192,40960)    probe region: (g*32+slot)*128B {data[2] @+0, flag @+64}
//   [40960,43008)   per-group flag lines: 32 ints dense, 256B stride
//   [73728,335872)  per-group h buffers: 2*4096*2B, stride 32768
#define OFF_CNT      1024
#define OFF_BAD      1056
#define OFF_PROBE    8192
#define PROBE_STRIDE 128
#define OFF_FLAGS    40960
#define FLAG_STRIDE  256
#define OFF_HB       73728
#define HB_STRIDE    32768

#define DYN_LDS      (88 * 1024)   // + ~15KB static -> 1 block/CU

typedef __bf16 bf16_t;
typedef __bf16 bf16x8 __attribute__((ext_vector_type(8)));
typedef float  f32x4  __attribute__((ext_vector_type(4)));
typedef unsigned uint4v __attribute__((ext_vector_type(4)));

__device__ __forceinline__ unsigned pack_bf16(float a, float b) {
    unsigned short lo = __builtin_bit_cast(unsigned short, (bf16_t)a);
    unsigned short hi = __builtin_bit_cast(unsigned short, (bf16_t)b);
    return (unsigned)lo | ((unsigned)hi << 16);
}

// Device-wide barrier with release/acquire agent fences (wbl2 / inv).
__device__ __forceinline__ void device_barrier(int* arrive, int bid, int tid, int target) {
    __builtin_amdgcn_fence(__ATOMIC_RELEASE, "agent");
    __syncthreads();
    if (tid < 64) {
        if (tid == 0)
            __hip_atomic_store(&arrive[bid], target, __ATOMIC_RELAXED, __HIP_MEMORY_SCOPE_AGENT);
        for (;;) {
            int v0 = __hip_atomic_load(&arrive[tid],       __ATOMIC_RELAXED, __HIP_MEMORY_SCOPE_AGENT);
            int v1 = __hip_atomic_load(&arrive[tid + 64],  __ATOMIC_RELAXED, __HIP_MEMORY_SCOPE_AGENT);
            int v2 = __hip_atomic_load(&arrive[tid + 128], __ATOMIC_RELAXED, __HIP_MEMORY_SCOPE_AGENT);
            int v3 = __hip_atomic_load(&arrive[tid + 192], __ATOMIC_RELAXED, __HIP_MEMORY_SCOPE_AGENT);
            if (__all((v0 >= target) & (v1 >= target) & (v2 >= target) & (v3 >= target))) break;
            __builtin_amdgcn_s_sleep(1);
        }
    }
    __syncthreads();
    __builtin_amdgcn_fence(__ATOMIC_ACQUIRE, "agent");
}

// LOCAL=true : plain store (write-through L1 -> XCD L2) + sc0 load (L1
//              bypass, reads XCD L2). Probe-validated before use.
// LOCAL=false: sc0 sc1 both ways (L3 coherence point) - R3's protocol.
template<bool LOCAL>
__device__ __forceinline__ void ld16(uint4v& r, const void* p) {
    if constexpr (LOCAL)
        asm volatile("global_load_dwordx4 %0, %1, off sc0" : "=&v"(r) : "v"(p) : "memory");
    else
        asm volatile("global_load_dwordx4 %0, %1, off sc0 sc1" : "=&v"(r) : "v"(p) : "memory");
}
template<bool LOCAL>
__device__ __forceinline__ void st32(void* p, unsigned v) {
    if constexpr (LOCAL)
        asm volatile("global_store_dword %0, %1, off" :: "v"(p), "v"(v) : "memory");
    else
        asm volatile("global_store_dword %0, %1, off sc0 sc1" :: "v"(p), "v"(v) : "memory");
}
template<bool LOCAL>
__device__ __forceinline__ int ldflag(const int* p) {
    int v;
    if constexpr (LOCAL)
        asm volatile("global_load_dword %0, %1, off sc0\n\ts_waitcnt vmcnt(0)"
                     : "=&v"(v) : "v"(p) : "memory");
    else
        asm volatile("global_load_dword %0, %1, off sc0 sc1\n\ts_waitcnt vmcnt(0)"
                     : "=&v"(v) : "v"(p) : "memory");
    return v;
}

template<bool LOCAL>
__device__ __forceinline__ void scan_loop(
    uint4v (&breg)[17],
    bf16_t* buf0, bf16_t* buf1,
    int* flags, int slot, int h0,
    float xreg, const float* xq,   // x[t] value; pointer to slice t+1
    float* outp, float bias_c,
    unsigned char* ldsA, float* ldsR, int* rel,
    int tid, int lane, int wv)
{
    const int quad = lane >> 4;
    const int mcol = lane & 15;
    const int kh   = wv >> 1;          // K half
    const int rr   = (mcol < 4) ? mcol : 4;  // A row (4 = LDS zero row)
    const int fb   = (tid >> 5) & 3;
    const int fcw  = tid & 31;
    const int fn   = fcw >> 4, fcc = fcw & 15;
    const int srow = wv;               // stage row = wave id
    const int sl   = lane;             // stage lane -> 16B chunk id
    int*       myflag = flags + slot;           // dense: one int per slot
    const int* pollp  = flags + (lane & 31);    // 32 flags in one 128B line
    float hp = 0.f;
    // MFMA A-fragment base in LDS (16B aligned: LSTR,1088,16 all %16==0)
    const uint4v* ap = (const uint4v*)(ldsA + rr * LSTR + kh * 1088 + quad * 16);

    #pragma unroll 1
    for (int t = 0; t < T_; ++t) {
        const bf16_t* cur  = (t & 1) ? buf1 : buf0;
        bf16_t*       nxtb = (t & 1) ? buf0 : buf1;

        // STAGE: cooperatively load rows 0-3 of cur (h only, 8KB) -> LDS.
        // Per thread: 2x16B chunks of its wave's row. x columns come from
        // the xreg register pipeline (read-only input, no protocol).
        uint4v s0, s1;
        {
            const bf16_t* sp = cur + srow * ROWE;
            ld16<LOCAL>(s0, sp + sl * 8);
            ld16<LOCAL>(s1, sp + sl * 8 + 512);
        }
        // vmcnt(0): retires s0,s1 AND last step's xreg load (issued before
        // them -> in-order retirement). Tie xreg so its use can't hoist.
        asm volatile("s_waitcnt vmcnt(0)"
                     : "+v"(s0), "+v"(s1), "+v"(xreg) :: "memory");
        *(uint4v*)(ldsA + srow * LSTR + sl * 16)        = s0;
        *(uint4v*)(ldsA + srow * LSTR + 1024 + sl * 16) = s1;
        *(bf16_t*)(ldsA + srow * LSTR + 2048 + sl * 2)  = (bf16_t)xreg;
        // Issue x load for slice t+1 (plain cached: x is read-only). Rides
        // out under MFMA+finish; retired at latest by next stage's vmcnt.
        if (t + 1 < T_) {
            asm volatile("global_load_dword %0, %1, off"
                         : "=v"(xreg) : "v"(xq) : "memory");
            xq += D_;
        }
        __syncthreads();

        // 17 MFMA from LDS A-fragments, 4 interleaved accumulator chains.
        f32x4 acc[4] = {{0.f,0.f,0.f,0.f},{0.f,0.f,0.f,0.f},
                        {0.f,0.f,0.f,0.f},{0.f,0.f,0.f,0.f}};
        #pragma unroll
        for (int kc = 0; kc < 17; ++kc) {
            uint4v a = ap[kc * 4];        // kc*64B
            acc[kc & 3] = __builtin_amdgcn_mfma_f32_16x16x32_bf16(
                __builtin_bit_cast(bf16x8, a),
                __builtin_bit_cast(bf16x8, breg[kc]), acc[kc & 3], 0, 0, 0);
        }
        f32x4 accs = (acc[0] + acc[1]) + (acc[2] + acc[3]);

        // Cross-wave K-half reduce via LDS. C/D: col=lane&15, row=quad*4+i.
        #pragma unroll
        for (int i = 0; i < 4; ++i)
            ldsR[wv * 256 + (quad * 4 + i) * 16 + mcol] = accs[i];
        __syncthreads();

        float hn = 0.f;
        if (tid < 128) {
            // wave (n_=fn,kh=0) = region fn; wave (n_=fn,kh=1) = region fn+2
            float s  = ldsR[fn * 256 + fb * 16 + fcc]
                     + ldsR[(fn + 2) * 256 + fb * 16 + fcc];
            float u  = s + bias_c;
            // tanh(u) = 1 - 2/(e^{2u}+1); saturates correctly at +-inf.
            float ex = __expf(2.f * u);
            float th = 1.f - 2.f * __builtin_amdgcn_rcpf(ex + 1.f);
            hn = (1.f - LRATE) * hp + LRATE * th;
            hp = hn;
            unsigned hbits = (unsigned)__builtin_bit_cast(unsigned short, (bf16_t)hn);
            unsigned hi    = __shfl_down(hbits, 1);
            if (!(tid & 1))
                st32<LOCAL>(nxtb + fb * ROWE + h0 + fcw, hbits | (hi << 16));
        }

        if (t + 1 < T_) {
            // Drain h-store acks (also retires the x load - normally long
            // since done; first-toucher residual hides under this wait).
            asm volatile("s_waitcnt vmcnt(0)" ::: "memory");
            __syncthreads();
            if (tid == 0)
                st32<LOCAL>(myflag, (unsigned)(t + 1));
            if (tid < 128) outp[(size_t)t * H_] = hn;   // off the drain path
            const int target = t + 1;
            if (wv == 0) {
                // SINGLE L2 POLLER: 2-deep pipelined poll. Outstanding at
                // first wait: [flag, out, p0, p1] -> vmcnt(1) retires
                // through p0 (in-order); loop keeps exactly one in flight.
                int v0 = 0, v1 = 0;
                #define PLD(r) do { if constexpr (LOCAL) \
                        asm volatile("global_load_dword %0, %1, off sc0" \
                                     : "=v"(r) : "v"(pollp) : "memory"); \
                    else \
                        asm volatile("global_load_dword %0, %1, off sc0 sc1" \
                                     : "=v"(r) : "v"(pollp) : "memory"); } while (0)
                PLD(v0); PLD(v1);
                for (;;) {
                    asm volatile("s_waitcnt vmcnt(1)" : "+v"(v0) :: "memory");
                    if (__all(v0 >= target)) break;
                    PLD(v0);
                    asm volatile("s_waitcnt vmcnt(1)" : "+v"(v1) :: "memory");
                    if (__all(v1 >= target)) break;
                    PLD(v1);
                }
                #undef PLD
                if (tid == 0)
                    __hip_atomic_store(rel, target, __ATOMIC_RELAXED,
                                       __HIP_MEMORY_SCOPE_WORKGROUP);
            } else {
                // LDS release spin: no L2 traffic.
                while (__hip_atomic_load(rel, __ATOMIC_RELAXED,
                                         __HIP_MEMORY_SCOPE_WORKGROUP) < target) {}
            }
            // Re-def xreg: consumers (next step's convert) ordered after.
            asm volatile("" : "+v"(xreg) :: );
        } else {
            if (tid < 128) outp[(size_t)t * H_] = hn;
        }
    }
}

__global__ __launch_bounds__(NTHR, 1) void esn_scan(
    const float* __restrict__ x,     // [B, T, D]
    const float* __restrict__ Win,   // [H, D]
    const float* __restrict__ bias,  // [H]
    const float* __restrict__ W,     // [H, H]
    float* __restrict__ out,         // [B, T, H]
    unsigned char* wsb)
{
    extern __shared__ unsigned char dynsmem[];   // occupancy ballast (88KB)
    __shared__ __align__(16) unsigned char ldsA[5 * LSTR]; // A stage + zero row
    __shared__ float ldsR[1024];                 // cross-wave reduce
    __shared__ int   rel;                        // poll release word
    __shared__ int   slot_sh;
    (void)dynsmem;

    int* darr = (int*)wsb;
    int* cnt  = (int*)(wsb + OFF_CNT);
    int* badp = (int*)(wsb + OFF_BAD);

    unsigned xcd;
    asm volatile("s_getreg_b32 %0, hwreg(HW_REG_XCC_ID)" : "=s"(xcd));
    xcd &= 7;

    const int tid  = threadIdx.x;
    const int bid  = blockIdx.x;
    const int lane = tid & 63;
    const int wv   = tid >> 6;

    if (tid == 0) slot_sh = atomicAdd(&cnt[xcd], 1);
    __syncthreads();
    const int slot_raw = slot_sh;

    device_barrier(darr, bid, tid, 1);

    // Symmetry: did every XCD get exactly 32 blocks?
    bool sym;
    {
        int c = __hip_atomic_load(&cnt[lane & 7], __ATOMIC_RELAXED, __HIP_MEMORY_SCOPE_AGENT);
        sym = __all(c == NSLOT);
    }
    const int g  = sym ? (int)xcd : (bid & 7);
    const int s  = sym ? slot_raw : (bid >> 3);
    const int h0 = s * 32;

    // ---- LOCAL-coherence probe (only when placement is symmetric) ----
    if (sym && tid == 0) {
        unsigned* pd = (unsigned*)(wsb + OFF_PROBE + ((size_t)g * NSLOT + s) * PROBE_STRIDE);
        unsigned* pf = pd + 16;   // +64B
        unsigned* nd = (unsigned*)(wsb + OFF_PROBE + ((size_t)g * NSLOT + ((s + 1) & 31)) * PROBE_STRIDE);
        unsigned* nf = nd + 16;
        int bad = 0;
        for (int round = 1; round <= 2 && !bad; ++round) {
            unsigned val = 0xA5000000u + ((unsigned)round << 16) + (unsigned)s;
            st32<true>(pd + (round & 1), val);
            asm volatile("s_waitcnt vmcnt(0)" ::: "memory");
            st32<true>(pf, (unsigned)round);
            unsigned fv = 0; int iters = 0;
            for (;;) {
                fv = (unsigned)ldflag<true>((const int*)nf);
                if (fv >= (unsigned)round) break;
                if (++iters > 8192) { bad = 1; break; }
            }
            if (!bad) {
                unsigned dv = (unsigned)ldflag<true>((const int*)(nd + (round & 1)));
                unsigned expect = 0xA5000000u + ((unsigned)round << 16) + (unsigned)((s + 1) & 31);
                if (dv != expect) bad = 1;
            }
        }
        if (bad) atomicOr(badp, 1);
    }

    device_barrier(darr, bid, tid, 2);

    int badv = __hip_atomic_load(badp, __ATOMIC_RELAXED, __HIP_MEMORY_SCOPE_AGENT);
    const bool local = sym && (badv == 0);

    int*    flags = (int*)(wsb + OFF_FLAGS + (size_t)g * FLAG_STRIDE);
    bf16_t* hb    = (bf16_t*)(wsb + OFF_HB + (size_t)g * HB_STRIDE);
    bf16_t* buf0  = hb;
    bf16_t* buf1  = hb + BUFE;

    // ---------------- init ----------------
    // buf0 h rows = 0 and all flags = 0: FREE from the harness ws memset
    // (same reliance as every passing round since R3). No x staging needed.
    // LDS: zero row 4 of ldsA (incl. its x columns); release word = 0.
    {
        unsigned* za = (unsigned*)(ldsA + 4 * LSTR);
        for (int j = tid; j < LSTR / 4; j += NTHR) za[j] = 0;
        if (tid == 0) rel = 0;
    }

    // B-fragments: W rows [h0,h0+32) (+ Win for k>=1024), bf16, registers.
    const int n_   = wv & 1;          // N-tile (16 cols)
    const int kh   = wv >> 1;         // K half [kh*544, kh*544+544)
    const int quad = lane >> 4;
    const int mcol = lane & 15;
    const int col  = h0 + n_ * 16 + mcol;

    uint4v breg[17];
    for (int kc = 0; kc < 17; ++kc) {
        int kb = kh * 544 + kc * 32 + quad * 8;
        float v[8];
        #pragma unroll
        for (int j = 0; j < 8; ++j) {
            int k = kb + j;
            v[j] = (k < H_) ? W[(size_t)col * H_ + k]
                            : Win[col * D_ + (k - H_)];
        }
        uint4v pk;
        pk[0] = pack_bf16(v[0], v[1]); pk[1] = pack_bf16(v[2], v[3]);
        pk[2] = pack_bf16(v[4], v[5]); pk[3] = pack_bf16(v[6], v[7]);
        breg[kc] = pk;
    }

    // Finisher state (waves 0-1): one (batch, col) per thread.
    const int fb  = (tid >> 5) & 3;
    const int fcw = tid & 31;
    const float bias_c = bias[h0 + fcw];
    float* outp = out + (size_t)(4 * g + fb) * (T_ * H_) + h0 + fcw;

    // x register pipeline: wave w lane l holds x[4g+w][t][l] (f32).
    const float* xbase = x + (size_t)(4 * g + wv) * (T_ * D_) + lane;
    float xreg;
    asm volatile("global_load_dword %0, %1, off" : "=v"(xreg) : "v"(xbase) : "memory");
    asm volatile("s_waitcnt vmcnt(0)" : "+v"(xreg) :: "memory");

    device_barrier(darr, bid, tid, 3);   // flushes init stores (wbl2)

    // ---------------- scan ----------------
    if (local)
        scan_loop<true >(breg, buf0, buf1, flags, s, h0,
                         xreg, xbase + D_, outp, bias_c,
                         ldsA, ldsR, &rel, tid, lane, wv);
    else
        scan_loop<false>(breg, buf0, buf1, flags, s, h0,
                         xreg, xbase + D_, outp, bias_c,
                         ldsA, ldsR, &rel, tid, lane, wv);
}

extern "C" void kernel_launch(void* const* d_in, const int* in_sizes, int n_in,
                              void* d_out, int out_size, void* d_ws, size_t ws_size,
                              hipStream_t stream) {
    (void)in_sizes; (void)n_in; (void)out_size; (void)ws_size;
    const float* x    = (const float*)d_in[0];
    const float* Win  = (const float*)d_in[1];
    const float* bias = (const float*)d_in[2];
    const float* W    = (const float*)d_in[3];
    float*       out  = (float*)d_out;
    void*        ws   = d_ws;

    static int attr_ok = -1;
    if (attr_ok < 0) {
        hipError_t ae = hipFuncSetAttribute((const void*)esn_scan,
                            hipFuncAttributeMaxDynamicSharedMemorySize, DYN_LDS);
        attr_ok = (ae == hipSuccess) ? 1 : 0;
    }

    void* args[] = { (void*)&x, (void*)&Win, (void*)&bias, (void*)&W, (void*)&out, (void*)&ws };
    hipError_t e = hipErrorUnknown;
    if (attr_ok == 1)
        e = hipLaunchCooperativeKernel((const void*)esn_scan, dim3(GRID), dim3(NTHR),
                                       args, DYN_LDS, stream);
    if (e != hipSuccess)
        e = hipLaunchCooperativeKernel((const void*)esn_scan, dim3(GRID), dim3(NTHR),
                                       args, 0, stream);
    if (e != hipSuccess)
        hipLaunchKernelGGL(esn_scan, dim3(GRID), dim3(NTHR), 0, stream,
                           x, Win, bias, W, out, (unsigned char*)ws);
}